// Round 10
// baseline (596.547 us; speedup 1.0000x reference)
//
#include <hip/hip_runtime.h>
#include <hip/hip_bf16.h>
#include <hip/hip_cooperative_groups.h>

namespace cg = cooperative_groups;

#define N_NODES 16384
#define N_EDGES 65536
#define NB      32
#define H       64
#define NLAYERS 3
#define NEG     0.1f
#define LN_EPS  1e-5f

typedef _Float16 f16;
typedef _Float16 f16x2 __attribute__((ext_vector_type(2)));
typedef _Float16 f16x8 __attribute__((ext_vector_type(8)));
typedef __fp16   hf16x2 __attribute__((ext_vector_type(2)));
typedef float    f32x16 __attribute__((ext_vector_type(16)));

union F16x8 { f16x8 v; f16x2 p[4]; int4 i4; int2 i2[2]; };
union F16x2U { f16x2 h2; hf16x2 raw; unsigned int u; };
union F16U   { f16 h; unsigned short u; };

__device__ __forceinline__ f16x2 pkrtz(float a, float b) {
    F16x2U t; t.raw = __builtin_amdgcn_cvt_pkrtz(a, b); return t.h2;
}
__device__ __forceinline__ float leaky(float v) { return v > 0.f ? v : NEG * v; }

#define HS_STRIDE 76   // u16; 152 B rows -> 2-way LDS banks (free)

// ---------------------------------------------------------------- LDS overlay
struct MsgSh {                       // 60928 B per half-block
    unsigned short hsL[128 * HS_STRIDE];
    unsigned short e1L[128 * 72];
    unsigned short e2L[128 * 72];
    float eas[128 * 8];
    int dstL[128];
};
struct NodeSh {                      // 26624 B (half 0 only)
    unsigned short hA[64 * 72];
    float outL[64][68];
};
struct HeadSh {                      // 20608 B
    float cntL[32];
    float ps[32][64];
    float p1[32][64];
    float p2[32][32];
};
union ShU { MsgSh m[2]; NodeSh n; HeadSh hd; };   // max 121856 B -> 1 block/CU

// ---------------------------------------------------------------- msg helpers (r0-proven)
__device__ __forceinline__ void loadB8(const f16* __restrict__ Bp, int c, int oq, int lane, F16x8* dstB) {
    const f16* base = Bp + (((size_t)(c * 16 + oq)) << 9) + lane * 8;
#pragma unroll
    for (int di = 0; di < 2; di++)
#pragma unroll
        for (int ks = 0; ks < 4; ks++)
            dstB[di * 4 + ks].i4 = *(const int4*)(base + ((di * 8 + ks * 2) << 9));
}
__device__ __forceinline__ void loadB4(const f16* __restrict__ Bp, int oq, int lane, F16x8* dstB) {
    const f16* base = Bp + (((size_t)(512 + oq)) << 9) + lane * 8;
#pragma unroll
    for (int ks = 0; ks < 4; ks++)
        dstB[ks].i4 = *(const int4*)(base + ((ks * 2) << 9));
}

__device__ __forceinline__ void msg_chunk2(int c, const F16x8* __restrict__ B,
                                           const unsigned short* hp0,
                                           const unsigned short* hp1,
                                           const f16x2 (*e2p)[4][4], f32x16* CC) {
    unsigned int rr0 = *(const unsigned int*)(hp0 + 2 * c);
    unsigned int rr1 = *(const unsigned int*)(hp1 + 2 * c);
    F16x2U h00, h01, h10, h11;
    h00.u = __builtin_amdgcn_perm(rr0, rr0, 0x01000100u);
    h10.u = __builtin_amdgcn_perm(rr0, rr0, 0x03020302u);
    h01.u = __builtin_amdgcn_perm(rr1, rr1, 0x01000100u);
    h11.u = __builtin_amdgcn_perm(rr1, rr1, 0x03020302u);
#pragma unroll
    for (int ks = 0; ks < 4; ks++) {
        F16x8 A00, A01, A10, A11;
#pragma unroll
        for (int r = 0; r < 4; r++) {
            A00.p[r] = h00.h2 * e2p[0][ks][r];
            A01.p[r] = h01.h2 * e2p[1][ks][r];
            A10.p[r] = h10.h2 * e2p[0][ks][r];
            A11.p[r] = h11.h2 * e2p[1][ks][r];
        }
        CC[0] = __builtin_amdgcn_mfma_f32_32x32x16_f16(A00.v, B[0 * 4 + ks].v, CC[0], 0, 0, 0);
        CC[1] = __builtin_amdgcn_mfma_f32_32x32x16_f16(A01.v, B[0 * 4 + ks].v, CC[1], 0, 0, 0);
        CC[2] = __builtin_amdgcn_mfma_f32_32x32x16_f16(A10.v, B[1 * 4 + ks].v, CC[2], 0, 0, 0);
        CC[3] = __builtin_amdgcn_mfma_f32_32x32x16_f16(A11.v, B[1 * 4 + ks].v, CC[3], 0, 0, 0);
    }
}

// ---------------------------------------------------------------- phase: msg (r0 body on a 128-edge half-block)
__device__ void msg_phase(MsgSh& S, int th, int ebh,
                          const float* __restrict__ h,
                          const float* __restrict__ ea,
                          const float* __restrict__ w1,
                          const float* __restrict__ b1,
                          const float* __restrict__ w2,
                          const float* __restrict__ b2,
                          const f16* __restrict__ Bp,
                          const int* __restrict__ src,
                          const int* __restrict__ dst,
                          float* __restrict__ agg) {
    const int lane = th & 63;
    const int wl   = th >> 6;            // 0..3 within half
    const int eh   = wl >> 1, oq = wl & 1;
    const int m    = lane & 31;
    const int kp   = lane >> 5;

    // ---- stage ea rows (5 -> pad 8)
    for (int idx = th; idx < 640; idx += 256) {
        int r = idx / 5, d = idx - r * 5;
        S.eas[r * 8 + d] = ea[(size_t)ebh * 5 + idx];
    }
    // ---- stage h rows (gathered by src): 2 threads per row
    {
        int e    = th >> 1;
        int half2 = th & 1;
        int nsrc = src[ebh + e];
        const float4* hr = (const float4*)(h + (size_t)nsrc * 64 + half2 * 32);
        unsigned int* hrow = (unsigned int*)S.hsL + e * (HS_STRIDE / 2) + half2 * 16;
#pragma unroll
        for (int q = 0; q < 8; q++) {
            float4 v = hr[q];
            F16x2U p0, p1;
            p0.raw = __builtin_amdgcn_cvt_pkrtz(v.x, v.y);
            p1.raw = __builtin_amdgcn_cvt_pkrtz(v.z, v.w);
            hrow[q * 2 + 0] = p0.u;
            hrow[q * 2 + 1] = p1.u;
        }
        if (th < 128) S.dstL[th] = dst[ebh + th];
    }
    __syncthreads();

    // ---- edge-MLP stage 1
    {
        int kk = th & 63;
        int eg = th >> 6;
        float w1r[5];
#pragma unroll
        for (int d = 0; d < 5; d++) w1r[d] = w1[kk * 5 + d];
        float b1r = b1[kk];
#pragma unroll 4
        for (int g = 0; g < 32; g++) {
            int row = eg * 32 + g;
            float4 a4 = *(const float4*)(S.eas + row * 8);
            float a5 = S.eas[row * 8 + 4];
            float v = b1r + a4.x * w1r[0] + a4.y * w1r[1] + a4.z * w1r[2] + a4.w * w1r[3] + a5 * w1r[4];
            F16U z; z.h = (f16)leaky(v);
            S.e1L[row * 72 + kk] = z.u;
        }
    }
    __syncthreads();

    // ---- edge-MLP stage 2 (MFMA)
    {
        F16x8 W2f[4];
#pragma unroll
        for (int ks = 0; ks < 4; ks++) {
            const float* s = w2 + (size_t)(oq * 32 + m) * 64 + ks * 16 + kp * 8;
            float4 a = ((const float4*)s)[0];
            float4 b = ((const float4*)s)[1];
            W2f[ks].p[0] = pkrtz(a.x, a.y);
            W2f[ks].p[1] = pkrtz(a.z, a.w);
            W2f[ks].p[2] = pkrtz(b.x, b.y);
            W2f[ks].p[3] = pkrtz(b.z, b.w);
        }
        float b2r = b2[oq * 32 + m];
#pragma unroll
        for (int tt = 0; tt < 2; tt++) {
            f32x16 C2 = {0,0,0,0,0,0,0,0,0,0,0,0,0,0,0,0};
#pragma unroll
            for (int ks = 0; ks < 4; ks++) {
                F16x8 A;
                A.i4 = *(const int4*)(S.e1L + (size_t)((eh * 2 + tt) * 32 + m) * 72 + ks * 16 + kp * 8);
                C2 = __builtin_amdgcn_mfma_f32_32x32x16_f16(A.v, W2f[ks].v, C2, 0, 0, 0);
            }
#pragma unroll
            for (int reg = 0; reg < 16; reg++) {
                int r = (reg & 3) + 8 * (reg >> 2) + 4 * kp;
                F16U z; z.h = (f16)leaky(C2[reg] + b2r);
                S.e2L[((eh * 2 + tt) * 32 + r) * 72 + oq * 32 + m] = z.u;
            }
        }
    }
    __syncthreads();

    // ---- read e2 A-operand pairs
    f16x2 e2p[2][4][4];
#pragma unroll
    for (int tt = 0; tt < 2; tt++) {
#pragma unroll
        for (int ks = 0; ks < 4; ks++) {
            F16x8 q;
            q.i4 = *(const int4*)(S.e2L + (size_t)((eh * 2 + tt) * 32 + m) * 72 + ks * 16 + kp * 8);
            e2p[tt][ks][0] = q.p[0]; e2p[tt][ks][1] = q.p[1];
            e2p[tt][ks][2] = q.p[2]; e2p[tt][ks][3] = q.p[3];
        }
    }

    f32x16 CC[4];
#pragma unroll
    for (int q = 0; q < 4; q++)
#pragma unroll
        for (int r = 0; r < 16; r++) CC[q][r] = 0.f;

    const unsigned short* hp0 = S.hsL + ((eh * 2 + 0) * 32 + m) * HS_STRIDE;
    const unsigned short* hp1 = S.hsL + ((eh * 2 + 1) * 32 + m) * HS_STRIDE;

    // ---- STATIC double-buffered barrier-free K-loop (r0-proven)
    F16x8 B0[8], B1[8];
    loadB8(Bp, 0, oq, lane, B0);
    loadB8(Bp, 1, oq, lane, B1);
    for (int it = 0; it < 15; it++) {
        int c = it * 2;
        msg_chunk2(c,     B0, hp0, hp1, e2p, CC);  loadB8(Bp, c + 2, oq, lane, B0);
        msg_chunk2(c + 1, B1, hp0, hp1, e2p, CC);  loadB8(Bp, c + 3, oq, lane, B1);
    }
    msg_chunk2(30, B0, hp0, hp1, e2p, CC);
    loadB4(Bp, oq, lane, B0);
    msg_chunk2(31, B1, hp0, hp1, e2p, CC);

    // ---- bias chunk
#pragma unroll
    for (int ks = 0; ks < 4; ks++) {
        int koff = (ks * 16 + kp * 8) * 2;
        const char* r0p = (const char*)S.hsL + (size_t)((eh * 2 + 0) * 32 + m) * (HS_STRIDE * 2) + koff;
        const char* r1p = (const char*)S.hsL + (size_t)((eh * 2 + 1) * 32 + m) * (HS_STRIDE * 2) + koff;
        F16x8 A0, A1;
        A0.i2[0] = *(const int2*)(r0p); A0.i2[1] = *(const int2*)(r0p + 8);
        A1.i2[0] = *(const int2*)(r1p); A1.i2[1] = *(const int2*)(r1p + 8);
        CC[0] = __builtin_amdgcn_mfma_f32_32x32x16_f16(A0.v, B0[ks].v, CC[0], 0, 0, 0);
        CC[1] = __builtin_amdgcn_mfma_f32_32x32x16_f16(A1.v, B0[ks].v, CC[1], 0, 0, 0);
    }

    // ---- scatter
    int o = oq * 32 + m;
#pragma unroll
    for (int reg = 0; reg < 16; reg++) {
        int r = (reg & 3) + 8 * (reg >> 2) + 4 * kp;
        atomicAdd(&agg[(size_t)S.dstL[(eh * 2 + 0) * 32 + r] * 64 + o], CC[0][reg] + CC[2][reg]);
    }
#pragma unroll
    for (int reg = 0; reg < 16; reg++) {
        int r = (reg & 3) + 8 * (reg >> 2) + 4 * kp;
        atomicAdd(&agg[(size_t)S.dstL[(eh * 2 + 1) * 32 + r] * 64 + o], CC[1][reg] + CC[3][reg]);
    }
}

// ---------------------------------------------------------------- fused cooperative kernel
// 256 blocks x 512 thr = 1 block/CU by construction (LDS 121856) ->
// cooperative capacity holds for ANY VGPR count (r9's suspected failure).
// Per-CU msg concurrency = 8 waves = identical to r0's 2x4-wave config.
__global__ __launch_bounds__(512, 2) void k_fused(
    const float* __restrict__ x, const float* __restrict__ ea,
    const int* __restrict__ src, const int* __restrict__ dst, const int* __restrict__ bat,
    const float* __restrict__ Win, const float* __restrict__ bin,
    const float* __restrict__ ew1, const float* __restrict__ eb1,
    const float* __restrict__ ew2, const float* __restrict__ eb2,
    const float* __restrict__ ew3, const float* __restrict__ eb3,
    const float* __restrict__ rw, const float* __restrict__ rb,
    const float* __restrict__ lg, const float* __restrict__ lb,
    const float* __restrict__ pw1, const float* __restrict__ pb1,
    const float* __restrict__ pw2, const float* __restrict__ pb2,
    const float* __restrict__ pw3, const float* __restrict__ pb3,
    float* __restrict__ h, float* __restrict__ agg, float* __restrict__ deg,
    float* __restrict__ pooled, f16* __restrict__ Bp, float* __restrict__ out) {

    __shared__ __align__(16) ShU sh;
    cg::grid_group grid = cg::this_grid();

    const int t    = threadIdx.x;        // 0..511
    const int lane = t & 63;
    const int w    = t >> 6;             // 0..7
    const int half = t >> 8;             // 0,1
    const int th   = t & 255;            // idx within half

    // ================= PHASE S: setup =================
    {
        int tg = blockIdx.x * 512 + t;   // 0..131071
#pragma unroll
        for (int r = 0; r < 8; r++) {    // input projection: 8 outputs/thread
            int idx = r * 131072 + tg;
            int n = idx >> 6, j = idx & 63;
            const float* xr = x + n * 4;
            const float* wr = Win + j * 4;
            float v = bin[j] + xr[0] * wr[0] + xr[1] * wr[1] + xr[2] * wr[2] + xr[3] * wr[3];
            h[idx] = leaky(v);
        }
        if (tg < N_EDGES) atomicAdd(&deg[dst[tg]], 1.0f);
        int wid = blockIdx.x * 8 + w;    // Bp prep: 1560 wave-slots over 2048 waves
        if (wid < 1560) {
            int l    = wid / 520;
            int slot = wid - l * 520;
            const float* ew3l = ew3 + (size_t)l * 262144;
            const float* eb3l = eb3 + (size_t)l * 4096;
            int i   = slot >> 3;
            int rem = slot & 7;
            int ks  = rem >> 1;
            int oq  = rem & 1;
            int o   = oq * 32 + (lane & 31);
            int k0  = ks * 16 + (lane >> 5) * 8;
            float v[8];
            if (i < 64) {
                const float* s = ew3l + ((size_t)(i * 64 + o)) * 64 + k0;
                float4 a = ((const float4*)s)[0];
                float4 b = ((const float4*)s)[1];
                v[0] = a.x; v[1] = a.y; v[2] = a.z; v[3] = a.w;
                v[4] = b.x; v[5] = b.y; v[6] = b.z; v[7] = b.w;
            } else {
#pragma unroll
                for (int j = 0; j < 8; j++) v[j] = eb3l[(k0 + j) * 64 + o];
            }
            union { int4 i4; f16 a[8]; } ov;
#pragma unroll
            for (int j = 0; j < 8; j++) ov.a[j] = (f16)v[j];
            *(int4*)(Bp + (size_t)l * 266240 + (size_t)slot * 512 + lane * 8) = ov.i4;
        }
    }
    grid.sync();

    // ================= layers =================
    for (int l = 0; l < NLAYERS; l++) {
        float* agg_l = agg + (size_t)l * N_NODES * H;
        // msg: block handles 256 edges as two independent 128-edge halves
        msg_phase(sh.m[half], th, blockIdx.x * 256 + half * 128,
                  h, ea, ew1 + l * 320, eb1 + l * 64,
                  ew2 + l * 4096, eb2 + l * 64,
                  Bp + (size_t)l * 266240, src, dst, agg_l);
        grid.sync();

        // node: proven 256-thread body on half 0; half 1 matches barriers
        {
            NodeSh& N = sh.n;
            const float* rwl = rw + l * 4096;
            const float* rbl = rb + l * 64;
            const float* lgl = lg + l * 64;
            const float* lbl = lb + l * 64;
            int last = (l == NLAYERS - 1) ? 1 : 0;
            int nb = blockIdx.x * 64;
            int wl = th >> 6;
            int nq = wl >> 1, oq = wl & 1;
            int m = lane & 31, kp = lane >> 5;

            F16x8 Bf[4];
            if (half == 0) {
                int r = th >> 2, c0 = (th & 3) * 16;
                const float4* hr = (const float4*)(h + (size_t)(nb + r) * 64 + c0);
                unsigned int* drow = (unsigned int*)N.hA + r * 36 + c0 / 2;
#pragma unroll
                for (int q = 0; q < 4; q++) {
                    float4 v = hr[q];
                    F16x2U p0, p1;
                    p0.raw = __builtin_amdgcn_cvt_pkrtz(v.x, v.y);
                    p1.raw = __builtin_amdgcn_cvt_pkrtz(v.z, v.w);
                    drow[q * 2] = p0.u; drow[q * 2 + 1] = p1.u;
                }
#pragma unroll
                for (int ks = 0; ks < 4; ks++) {
                    const float* s = rwl + (size_t)(oq * 32 + m) * 64 + ks * 16 + kp * 8;
                    float4 a = ((const float4*)s)[0];
                    float4 b = ((const float4*)s)[1];
                    Bf[ks].p[0] = pkrtz(a.x, a.y);
                    Bf[ks].p[1] = pkrtz(a.z, a.w);
                    Bf[ks].p[2] = pkrtz(b.x, b.y);
                    Bf[ks].p[3] = pkrtz(b.z, b.w);
                }
            }
            __syncthreads();
            if (half == 0) {
                f32x16 C = {0,0,0,0,0,0,0,0,0,0,0,0,0,0,0,0};
#pragma unroll
                for (int ks = 0; ks < 4; ks++) {
                    F16x8 A;
                    A.i4 = *(const int4*)(N.hA + (size_t)(nq * 32 + m) * 72 + ks * 16 + kp * 8);
                    C = __builtin_amdgcn_mfma_f32_32x32x16_f16(A.v, Bf[ks].v, C, 0, 0, 0);
                }
                int o = oq * 32 + m;
#pragma unroll
                for (int reg = 0; reg < 16; reg++) {
                    int r = (reg & 3) + 8 * (reg >> 2) + 4 * kp;
                    int n = nq * 32 + r;
                    N.outL[n][o] = C[reg] + rbl[o] + agg_l[(size_t)(nb + n) * 64 + o] / fmaxf(deg[nb + n], 1.0f);
                }
            }
            __syncthreads();
            if (half == 0) {
                float gj = lgl[lane], bj = lbl[lane];
                float accp = 0.f;
                int cur = bat[nb + wl * 16];
                for (int q = 0; q < 16; q++) {
                    int n = wl * 16 + q;
                    float v = N.outL[n][lane];
                    float mu = v;
#pragma unroll
                    for (int msk = 32; msk > 0; msk >>= 1) mu += __shfl_xor(mu, msk);
                    mu *= (1.f / 64.f);
                    float d = v - mu;
                    float var = d * d;
#pragma unroll
                    for (int msk = 32; msk > 0; msk >>= 1) var += __shfl_xor(var, msk);
                    var *= (1.f / 64.f);
                    float ov = d * rsqrtf(var + LN_EPS) * gj + bj;
                    float hn = leaky(ov) + h[(size_t)(nb + n) * 64 + lane];
                    h[(size_t)(nb + n) * 64 + lane] = hn;
                    if (last) {
                        int b = bat[nb + n];
                        if (b != cur) { atomicAdd(&pooled[cur * 64 + lane], accp); accp = 0.f; cur = b; }
                        accp += hn;
                    }
                }
                if (last) atomicAdd(&pooled[cur * 64 + lane], accp);
            }
            __syncthreads();
        }
        grid.sync();
    }

    // ================= PHASE H: prediction head (block 0, 512 threads) =================
    if (blockIdx.x == 0) {
        HeadSh& Hh = sh.hd;
        if (t < 32) Hh.cntL[t] = 0.f;
        __syncthreads();
        {
            const int4* bp4 = (const int4*)(bat + t * 32);
            int cur = bat[t * 32];
            float c = 0.f;
            for (int q = 0; q < 8; q++) {
                int4 b4 = bp4[q];
                int bs[4] = { b4.x, b4.y, b4.z, b4.w };
#pragma unroll
                for (int e = 0; e < 4; e++) {
                    if (bs[e] != cur) { atomicAdd(&Hh.cntL[cur], c); cur = bs[e]; c = 0.f; }
                    c += 1.f;
                }
            }
            atomicAdd(&Hh.cntL[cur], c);
        }
        __syncthreads();
        for (int idx = t; idx < 2048; idx += 512) {
            int b = idx >> 6, j = idx & 63;
            Hh.ps[b][j] = pooled[idx] / fmaxf(Hh.cntL[b], 1.0f);
        }
        __syncthreads();
        for (int idx = t; idx < 2048; idx += 512) {
            int b = idx >> 6, j = idx & 63;
            float v = pb1[j];
#pragma unroll 8
            for (int i = 0; i < 64; i++) v += Hh.ps[b][i] * pw1[j * 64 + i];
            Hh.p1[b][j] = leaky(v);
        }
        __syncthreads();
        for (int idx = t; idx < 1024; idx += 512) {
            int b = idx >> 5, j = idx & 31;
            float v = pb2[j];
#pragma unroll 8
            for (int i = 0; i < 64; i++) v += Hh.p1[b][i] * pw2[j * 64 + i];
            Hh.p2[b][j] = leaky(v);
        }
        __syncthreads();
        if (t < 32) {
            float v = pb3[0];
#pragma unroll 8
            for (int i = 0; i < 32; i++) v += Hh.p2[t][i] * pw3[i];
            out[t] = v;
        }
    }
}

// ----------------------------------------------------------------
extern "C" void kernel_launch(void* const* d_in, const int* in_sizes, int n_in,
                              void* d_out, int out_size, void* d_ws, size_t ws_size,
                              hipStream_t stream) {
    const float* x    = (const float*)d_in[0];
    const int*   eidx = (const int*)  d_in[1];
    const float* ea   = (const float*)d_in[2];
    const int*   bat  = (const int*)  d_in[3];
    const float* Win  = (const float*)d_in[4];
    const float* bin  = (const float*)d_in[5];
    const float* ew1  = (const float*)d_in[6];
    const float* eb1  = (const float*)d_in[7];
    const float* ew2  = (const float*)d_in[8];
    const float* eb2  = (const float*)d_in[9];
    const float* ew3  = (const float*)d_in[10];
    const float* eb3  = (const float*)d_in[11];
    const float* rw   = (const float*)d_in[12];
    const float* rb   = (const float*)d_in[13];
    const float* lg   = (const float*)d_in[14];
    const float* lb   = (const float*)d_in[15];
    const float* pw1  = (const float*)d_in[16];
    const float* pb1  = (const float*)d_in[17];
    const float* pw2  = (const float*)d_in[18];
    const float* pb2  = (const float*)d_in[19];
    const float* pw3  = (const float*)d_in[20];
    const float* pb3  = (const float*)d_in[21];
    float* out = (float*)d_out;

    float* ws     = (float*)d_ws;
    float* h      = ws;                          // 1048576
    float* agg    = ws + 1048576;                // 3 * 1048576
    float* deg    = ws + 4194304;                // 16384
    float* pooled = ws + 4210688;                // 2048 (+64 pad)
    f16*   Bp     = (f16*)(ws + 4212800);        // 3 * 266240 f16

    const int* srcp = eidx;
    const int* dstp = eidx + N_EDGES;

    // one memset covers agg[3] + deg + pooled (contiguous)
    (void)hipMemsetAsync(agg, 0, (size_t)3164224 * sizeof(float), stream);

    void* args[] = {
        (void*)&x, (void*)&ea, (void*)&srcp, (void*)&dstp, (void*)&bat,
        (void*)&Win, (void*)&bin,
        (void*)&ew1, (void*)&eb1, (void*)&ew2, (void*)&eb2,
        (void*)&ew3, (void*)&eb3,
        (void*)&rw, (void*)&rb, (void*)&lg, (void*)&lb,
        (void*)&pw1, (void*)&pb1, (void*)&pw2, (void*)&pb2,
        (void*)&pw3, (void*)&pb3,
        (void*)&h, (void*)&agg, (void*)&deg, (void*)&pooled, (void*)&Bp, (void*)&out
    };
    (void)hipLaunchCooperativeKernel((void*)k_fused, dim3(256), dim3(512),
                                     args, 0, stream);
}

// Round 11
// 356.208 us; speedup vs baseline: 1.6747x; 1.6747x over previous
//
#include <hip/hip_runtime.h>
#include <hip/hip_bf16.h>

#define N_NODES 16384
#define N_EDGES 65536
#define NB      32
#define H       64
#define NLAYERS 3
#define NEG     0.1f
#define LN_EPS  1e-5f

typedef _Float16 f16;
typedef _Float16 f16x2 __attribute__((ext_vector_type(2)));
typedef _Float16 f16x8 __attribute__((ext_vector_type(8)));
typedef __fp16   hf16x2 __attribute__((ext_vector_type(2)));
typedef float    f32x16 __attribute__((ext_vector_type(16)));

union F16x8 { f16x8 v; f16x2 p[4]; int4 i4; int2 i2[2]; };
union F16x2U { f16x2 h2; hf16x2 raw; unsigned int u; };
union F16U   { f16 h; unsigned short u; };

__device__ __forceinline__ f16x2 pkrtz(float a, float b) {
    F16x2U t; t.raw = __builtin_amdgcn_cvt_pkrtz(a, b); return t.h2;
}
__device__ __forceinline__ float leaky(float v) { return v > 0.f ? v : NEG * v; }

// ---------------------------------------------------------------- setup: degree + Bp prep only (inproj is inlined into layer 0)
// Bp slot = i*8 + ks*2 + oq (i in [0,64]; i==64 = eb3 bias). layer stride 520 slots.
__global__ __launch_bounds__(256) void k_setup(const int* __restrict__ dst,
                                               const float* __restrict__ ew3,
                                               const float* __restrict__ eb3,
                                               float* __restrict__ deg,
                                               f16* __restrict__ Bp) {
    int bid = blockIdx.x;
    if (bid < 256) {                        // degree atomics (deg pre-zeroed by memset)
        int e = bid * 256 + threadIdx.x;
        atomicAdd(&deg[dst[e]], 1.0f);
    } else {                                // Bp prep: 390 blocks = 1560 slots
        int tg    = (bid - 256) * 256 + threadIdx.x;
        int lane  = tg & 63;
        int gslot = tg >> 6;
        int l     = gslot / 520;
        int slot  = gslot - l * 520;
        const float* ew3l = ew3 + (size_t)l * 262144;
        const float* eb3l = eb3 + (size_t)l * 4096;
        int i   = slot >> 3;
        int rem = slot & 7;
        int ks  = rem >> 1;
        int oq  = rem & 1;
        int o   = oq * 32 + (lane & 31);
        int k0  = ks * 16 + (lane >> 5) * 8;
        float v[8];
        if (i < 64) {
            const float* s = ew3l + ((size_t)(i * 64 + o)) * 64 + k0;
            float4 a = ((const float4*)s)[0];
            float4 b = ((const float4*)s)[1];
            v[0] = a.x; v[1] = a.y; v[2] = a.z; v[3] = a.w;
            v[4] = b.x; v[5] = b.y; v[6] = b.z; v[7] = b.w;
        } else {
#pragma unroll
            for (int j = 0; j < 8; j++) v[j] = eb3l[(k0 + j) * 64 + o];
        }
        union { int4 i4; f16 a[8]; } out;
#pragma unroll
        for (int j = 0; j < 8; j++) out.a[j] = (f16)v[j];
        *(int4*)(Bp + (size_t)l * 266240 + (size_t)slot * 512 + lane * 8) = out.i4;
    }
}

// ---------------------------------------------------------------- fused edge-MLP + bilinear MFMA GEMM + scatter
// r0-proven structure (best measured 52.4us). NEW: layer 0 computes h0 rows
// inline from x@Win^T (4 MACs/elem) instead of reading a precomputed h buffer
// -> the whole inproj dispatch-work disappears. Math is bit-identical (same
// f32 formula, same f16 rounding point).
#define HS_STRIDE 76   // u16; 152 B rows -> 2-way LDS banks (free)

__device__ __forceinline__ void loadB8(const f16* __restrict__ Bp, int c, int oq, int lane, F16x8* dstB) {
    const f16* base = Bp + (((size_t)(c * 16 + oq)) << 9) + lane * 8;
#pragma unroll
    for (int di = 0; di < 2; di++)
#pragma unroll
        for (int ks = 0; ks < 4; ks++)
            dstB[di * 4 + ks].i4 = *(const int4*)(base + ((di * 8 + ks * 2) << 9));
}
__device__ __forceinline__ void loadB4(const f16* __restrict__ Bp, int oq, int lane, F16x8* dstB) {
    const f16* base = Bp + (((size_t)(512 + oq)) << 9) + lane * 8;
#pragma unroll
    for (int ks = 0; ks < 4; ks++)
        dstB[ks].i4 = *(const int4*)(base + ((ks * 2) << 9));
}

__device__ __forceinline__ void msg_chunk2(int c, const F16x8* __restrict__ B,
                                           const unsigned short* hp0,
                                           const unsigned short* hp1,
                                           const f16x2 (*e2p)[4][4], f32x16* CC) {
    unsigned int rr0 = *(const unsigned int*)(hp0 + 2 * c);
    unsigned int rr1 = *(const unsigned int*)(hp1 + 2 * c);
    F16x2U h00, h01, h10, h11;
    h00.u = __builtin_amdgcn_perm(rr0, rr0, 0x01000100u);
    h10.u = __builtin_amdgcn_perm(rr0, rr0, 0x03020302u);
    h01.u = __builtin_amdgcn_perm(rr1, rr1, 0x01000100u);
    h11.u = __builtin_amdgcn_perm(rr1, rr1, 0x03020302u);
#pragma unroll
    for (int ks = 0; ks < 4; ks++) {
        F16x8 A00, A01, A10, A11;
#pragma unroll
        for (int r = 0; r < 4; r++) {
            A00.p[r] = h00.h2 * e2p[0][ks][r];
            A01.p[r] = h01.h2 * e2p[1][ks][r];
            A10.p[r] = h10.h2 * e2p[0][ks][r];
            A11.p[r] = h11.h2 * e2p[1][ks][r];
        }
        CC[0] = __builtin_amdgcn_mfma_f32_32x32x16_f16(A00.v, B[0 * 4 + ks].v, CC[0], 0, 0, 0);
        CC[1] = __builtin_amdgcn_mfma_f32_32x32x16_f16(A01.v, B[0 * 4 + ks].v, CC[1], 0, 0, 0);
        CC[2] = __builtin_amdgcn_mfma_f32_32x32x16_f16(A10.v, B[1 * 4 + ks].v, CC[2], 0, 0, 0);
        CC[3] = __builtin_amdgcn_mfma_f32_32x32x16_f16(A11.v, B[1 * 4 + ks].v, CC[3], 0, 0, 0);
    }
}

__global__ __launch_bounds__(256, 2) void k_msg(const float* __restrict__ h,
                                                const float* __restrict__ x,
                                                const float* __restrict__ Win,
                                                const float* __restrict__ bin,
                                                int first,
                                                const float* __restrict__ ea,
                                                const float* __restrict__ w1,
                                                const float* __restrict__ b1,
                                                const float* __restrict__ w2,
                                                const float* __restrict__ b2,
                                                const f16* __restrict__ Bp,
                                                const int* __restrict__ src,
                                                const int* __restrict__ dst,
                                                float* __restrict__ agg) {
    __shared__ __align__(16) unsigned short hsL[128 * HS_STRIDE];  // 19.5 KB
    __shared__ __align__(16) unsigned short e1L[128 * 72];         // 18 KB
    __shared__ __align__(16) unsigned short e2L[128 * 72];         // 18 KB
    __shared__ float eas[128 * 8];                                 // 4 KB
    __shared__ int dstL[128];

    const int t    = threadIdx.x;
    const int lane = t & 63;
    const int w    = t >> 6;
    const int eh   = w >> 1, oq = w & 1;
    const int m    = lane & 31;
    const int kp   = lane >> 5;
    const int eb   = blockIdx.x * 128;

    // ---- stage ea rows (5 -> pad 8)
    for (int idx = t; idx < 640; idx += 256) {
        int r = idx / 5, d = idx - r * 5;
        eas[r * 8 + d] = ea[(size_t)eb * 5 + idx];
    }
    // ---- stage h rows (gathered by src, fp32 -> f16): 2 threads per row.
    // layer 0: compute h0 = leaky(x@Win^T+b) inline (cheaper than a gather)
    {
        int e    = t >> 1;
        int half = t & 1;
        int nsrc = src[eb + e];
        unsigned int* hrow = (unsigned int*)hsL + e * (HS_STRIDE / 2) + half * 16;
        if (first) {
            float4 xr = *(const float4*)(x + (size_t)nsrc * 4);
            const float4* wr = (const float4*)Win + half * 32;   // rows j=half*32..
            const float* bb = bin + half * 32;
#pragma unroll
            for (int q = 0; q < 16; q++) {
                float4 w0 = wr[q * 2], w1 = wr[q * 2 + 1];
                float v0 = bb[q * 2]     + xr.x * w0.x + xr.y * w0.y + xr.z * w0.z + xr.w * w0.w;
                float v1 = bb[q * 2 + 1] + xr.x * w1.x + xr.y * w1.y + xr.z * w1.z + xr.w * w1.w;
                F16x2U p; p.raw = __builtin_amdgcn_cvt_pkrtz(leaky(v0), leaky(v1));
                hrow[q] = p.u;
            }
        } else {
            const float4* hr = (const float4*)(h + (size_t)nsrc * 64 + half * 32);
#pragma unroll
            for (int q = 0; q < 8; q++) {
                float4 v = hr[q];
                F16x2U p0, p1;
                p0.raw = __builtin_amdgcn_cvt_pkrtz(v.x, v.y);
                p1.raw = __builtin_amdgcn_cvt_pkrtz(v.z, v.w);
                hrow[q * 2 + 0] = p0.u;
                hrow[q * 2 + 1] = p1.u;
            }
        }
        if (t < 128) dstL[t] = dst[eb + t];
    }
    __syncthreads();

    // ---- edge-MLP stage 1: e1 = leaky(ea @ w1^T + b1) -> e1L (f16)
    {
        int kk = t & 63;
        int eg = t >> 6;
        float w1r[5];
#pragma unroll
        for (int d = 0; d < 5; d++) w1r[d] = w1[kk * 5 + d];
        float b1r = b1[kk];
#pragma unroll 4
        for (int g = 0; g < 32; g++) {
            int row = eg * 32 + g;
            float4 a4 = *(const float4*)(eas + row * 8);
            float a5 = eas[row * 8 + 4];
            float v = b1r + a4.x * w1r[0] + a4.y * w1r[1] + a4.z * w1r[2] + a4.w * w1r[3] + a5 * w1r[4];
            F16U z; z.h = (f16)leaky(v);
            e1L[row * 72 + kk] = z.u;
        }
    }
    __syncthreads();

    // ---- edge-MLP stage 2 (MFMA): wave (eh, oq) -> tiles eh*2+tt, k_out half oq
    {
        F16x8 W2f[4];
#pragma unroll
        for (int ks = 0; ks < 4; ks++) {
            const float* s = w2 + (size_t)(oq * 32 + m) * 64 + ks * 16 + kp * 8;
            float4 a = ((const float4*)s)[0];
            float4 b = ((const float4*)s)[1];
            W2f[ks].p[0] = pkrtz(a.x, a.y);
            W2f[ks].p[1] = pkrtz(a.z, a.w);
            W2f[ks].p[2] = pkrtz(b.x, b.y);
            W2f[ks].p[3] = pkrtz(b.z, b.w);
        }
        float b2r = b2[oq * 32 + m];
#pragma unroll
        for (int tt = 0; tt < 2; tt++) {
            f32x16 C2 = {0,0,0,0,0,0,0,0,0,0,0,0,0,0,0,0};
#pragma unroll
            for (int ks = 0; ks < 4; ks++) {
                F16x8 A;
                A.i4 = *(const int4*)(e1L + (size_t)((eh * 2 + tt) * 32 + m) * 72 + ks * 16 + kp * 8);
                C2 = __builtin_amdgcn_mfma_f32_32x32x16_f16(A.v, W2f[ks].v, C2, 0, 0, 0);
            }
#pragma unroll
            for (int reg = 0; reg < 16; reg++) {
                int r = (reg & 3) + 8 * (reg >> 2) + 4 * kp;
                F16U z; z.h = (f16)leaky(C2[reg] + b2r);
                e2L[((eh * 2 + tt) * 32 + r) * 72 + oq * 32 + m] = z.u;
            }
        }
    }
    __syncthreads();

    // ---- read e2 A-operand pairs for this wave's 2 tiles (full k)
    f16x2 e2p[2][4][4];
#pragma unroll
    for (int tt = 0; tt < 2; tt++) {
#pragma unroll
        for (int ks = 0; ks < 4; ks++) {
            F16x8 q;
            q.i4 = *(const int4*)(e2L + (size_t)((eh * 2 + tt) * 32 + m) * 72 + ks * 16 + kp * 8);
            e2p[tt][ks][0] = q.p[0]; e2p[tt][ks][1] = q.p[1];
            e2p[tt][ks][2] = q.p[2]; e2p[tt][ks][3] = q.p[3];
        }
    }

    f32x16 CC[4];
#pragma unroll
    for (int q = 0; q < 4; q++)
#pragma unroll
        for (int r = 0; r < 16; r++) CC[q][r] = 0.f;

    const unsigned short* hp0 = hsL + ((eh * 2 + 0) * 32 + m) * HS_STRIDE;
    const unsigned short* hp1 = hsL + ((eh * 2 + 1) * 32 + m) * HS_STRIDE;

    // ---- STATIC double-buffered barrier-free K-loop (r0-proven)
    F16x8 B0[8], B1[8];
    loadB8(Bp, 0, oq, lane, B0);
    loadB8(Bp, 1, oq, lane, B1);
    for (int it = 0; it < 15; it++) {
        int c = it * 2;
        msg_chunk2(c,     B0, hp0, hp1, e2p, CC);  loadB8(Bp, c + 2, oq, lane, B0);
        msg_chunk2(c + 1, B1, hp0, hp1, e2p, CC);  loadB8(Bp, c + 3, oq, lane, B1);
    }
    msg_chunk2(30, B0, hp0, hp1, e2p, CC);
    loadB4(Bp, oq, lane, B0);               // bias frags into B0[0..3]
    msg_chunk2(31, B1, hp0, hp1, e2p, CC);

    // ---- bias chunk: A = h itself (k plays the i role), B = eb3 frags
#pragma unroll
    for (int ks = 0; ks < 4; ks++) {
        int koff = (ks * 16 + kp * 8) * 2;
        const char* r0p = (const char*)hsL + (size_t)((eh * 2 + 0) * 32 + m) * (HS_STRIDE * 2) + koff;
        const char* r1p = (const char*)hsL + (size_t)((eh * 2 + 1) * 32 + m) * (HS_STRIDE * 2) + koff;
        F16x8 A0, A1;
        A0.i2[0] = *(const int2*)(r0p); A0.i2[1] = *(const int2*)(r0p + 8);
        A1.i2[0] = *(const int2*)(r1p); A1.i2[1] = *(const int2*)(r1p + 8);
        CC[0] = __builtin_amdgcn_mfma_f32_32x32x16_f16(A0.v, B0[ks].v, CC[0], 0, 0, 0);
        CC[1] = __builtin_amdgcn_mfma_f32_32x32x16_f16(A1.v, B0[ks].v, CC[1], 0, 0, 0);
    }

    // ---- merge i-parity chains, scatter
    int o = oq * 32 + m;
#pragma unroll
    for (int reg = 0; reg < 16; reg++) {
        int r = (reg & 3) + 8 * (reg >> 2) + 4 * kp;
        atomicAdd(&agg[(size_t)dstL[(eh * 2 + 0) * 32 + r] * 64 + o], CC[0][reg] + CC[2][reg]);
    }
#pragma unroll
    for (int reg = 0; reg < 16; reg++) {
        int r = (reg & 3) + 8 * (reg >> 2) + 4 * kp;
        atomicAdd(&agg[(size_t)dstL[(eh * 2 + 1) * 32 + r] * 64 + o], CC[1][reg] + CC[3][reg]);
    }
}

// ---------------------------------------------------------------- node update: MFMA root GEMM + LN + residual (+pool on last)
// layer 0: h0 computed inline from x (no h buffer read). Last layer: the
// LAST block to finish pooling (device-scope ticket) runs the prediction
// head in-kernel -> the k_head dispatch disappears.
struct NodeSh { unsigned short hA[64 * 72]; float outL[64][68]; };
struct HeadSh { float cntL[32]; float ps[32][64]; float p1[32][64]; float p2[32][32]; };
union NodeU { NodeSh n; HeadSh hd; };

__global__ __launch_bounds__(256) void k_node(const float* __restrict__ agg,
                                              const float* __restrict__ deg,
                                              const float* __restrict__ rw,
                                              const float* __restrict__ rb,
                                              const float* __restrict__ lg,
                                              const float* __restrict__ lb,
                                              float* __restrict__ h,
                                              const float* __restrict__ x,
                                              const float* __restrict__ Win,
                                              const float* __restrict__ bin,
                                              const int* __restrict__ batch,
                                              float* __restrict__ pooled,
                                              int first, int last,
                                              int* __restrict__ done,
                                              const float* __restrict__ pw1, const float* __restrict__ pb1,
                                              const float* __restrict__ pw2, const float* __restrict__ pb2,
                                              const float* __restrict__ pw3, const float* __restrict__ pb3,
                                              float* __restrict__ out) {
    __shared__ __align__(16) NodeU sh;
    __shared__ int isLastBlk;
    int t = threadIdx.x;
    int nb = blockIdx.x * 64;
    int lane = t & 63, w = t >> 6;
    int nq = w >> 1, oq = w & 1;
    int m = lane & 31, kp = lane >> 5;

    {
        int r = t >> 2, c0 = (t & 3) * 16;
        unsigned int* drow = (unsigned int*)sh.n.hA + r * 36 + c0 / 2;
        if (first) {
            float4 xr = *(const float4*)(x + (size_t)(nb + r) * 4);
            const float4* wrp = (const float4*)Win + c0;
            const float* bb = bin + c0;
#pragma unroll
            for (int q = 0; q < 8; q++) {
                float4 w0 = wrp[q * 2], w1 = wrp[q * 2 + 1];
                float v0 = bb[q * 2]     + xr.x * w0.x + xr.y * w0.y + xr.z * w0.z + xr.w * w0.w;
                float v1 = bb[q * 2 + 1] + xr.x * w1.x + xr.y * w1.y + xr.z * w1.z + xr.w * w1.w;
                F16x2U p; p.raw = __builtin_amdgcn_cvt_pkrtz(leaky(v0), leaky(v1));
                drow[q] = p.u;
            }
        } else {
            const float4* hr = (const float4*)(h + (size_t)(nb + r) * 64 + c0);
#pragma unroll
            for (int q = 0; q < 4; q++) {
                float4 v = hr[q];
                F16x2U p0, p1;
                p0.raw = __builtin_amdgcn_cvt_pkrtz(v.x, v.y);
                p1.raw = __builtin_amdgcn_cvt_pkrtz(v.z, v.w);
                drow[q * 2] = p0.u; drow[q * 2 + 1] = p1.u;
            }
        }
    }
    F16x8 Bf[4];
#pragma unroll
    for (int ks = 0; ks < 4; ks++) {
        const float* s = rw + (size_t)(oq * 32 + m) * 64 + ks * 16 + kp * 8;
        float4 a = ((const float4*)s)[0];
        float4 b = ((const float4*)s)[1];
        Bf[ks].p[0] = pkrtz(a.x, a.y);
        Bf[ks].p[1] = pkrtz(a.z, a.w);
        Bf[ks].p[2] = pkrtz(b.x, b.y);
        Bf[ks].p[3] = pkrtz(b.z, b.w);
    }
    __syncthreads();

    f32x16 C = {0,0,0,0,0,0,0,0,0,0,0,0,0,0,0,0};
#pragma unroll
    for (int ks = 0; ks < 4; ks++) {
        F16x8 A;
        A.i4 = *(const int4*)(sh.n.hA + (size_t)(nq * 32 + m) * 72 + ks * 16 + kp * 8);
        C = __builtin_amdgcn_mfma_f32_32x32x16_f16(A.v, Bf[ks].v, C, 0, 0, 0);
    }

    int o = oq * 32 + m;
#pragma unroll
    for (int reg = 0; reg < 16; reg++) {
        int r = (reg & 3) + 8 * (reg >> 2) + 4 * kp;
        int n = nq * 32 + r;
        sh.n.outL[n][o] = C[reg] + rb[o] + agg[(size_t)(nb + n) * 64 + o] / fmaxf(deg[nb + n], 1.0f);
    }
    __syncthreads();

    {
        float gj = lg[lane], bj = lb[lane];
        float wr0 = 0.f, wr1 = 0.f, wr2 = 0.f, wr3 = 0.f, br = 0.f;
        if (first) {
            wr0 = Win[lane * 4 + 0]; wr1 = Win[lane * 4 + 1];
            wr2 = Win[lane * 4 + 2]; wr3 = Win[lane * 4 + 3];
            br  = bin[lane];
        }
        float accp = 0.f;
        int cur = batch[nb + w * 16];
        for (int q = 0; q < 16; q++) {
            int n = w * 16 + q;
            float v = sh.n.outL[n][lane];
            float mu = v;
#pragma unroll
            for (int msk = 32; msk > 0; msk >>= 1) mu += __shfl_xor(mu, msk);
            mu *= (1.f / 64.f);
            float d = v - mu;
            float var = d * d;
#pragma unroll
            for (int msk = 32; msk > 0; msk >>= 1) var += __shfl_xor(var, msk);
            var *= (1.f / 64.f);
            float ov = d * rsqrtf(var + LN_EPS) * gj + bj;
            float hprev;
            if (first) {
                float4 xr = *(const float4*)(x + (size_t)(nb + n) * 4);
                hprev = leaky(br + xr.x * wr0 + xr.y * wr1 + xr.z * wr2 + xr.w * wr3);
            } else {
                hprev = h[(size_t)(nb + n) * 64 + lane];
            }
            float hn = leaky(ov) + hprev;
            h[(size_t)(nb + n) * 64 + lane] = hn;
            if (last) {
                int b = batch[nb + n];
                if (b != cur) { atomicAdd(&pooled[cur * 64 + lane], accp); accp = 0.f; cur = b; }
                accp += hn;
            }
        }
        if (last) atomicAdd(&pooled[cur * 64 + lane], accp);
    }

    // ---- last-block ticket: winner runs the prediction head in-kernel
    if (last) {
        __threadfence();
        if (t == 0) isLastBlk = (atomicAdd(done, 1) == (int)gridDim.x - 1) ? 1 : 0;
        __syncthreads();                    // also guarantees all outL reads done
        if (!isLastBlk) return;

        HeadSh& Hh = sh.hd;
        if (t < 32) Hh.cntL[t] = 0.f;
        __syncthreads();
        {
            const int4* bp4 = (const int4*)(batch + t * 64);
            int cur = batch[t * 64];
            float c = 0.f;
            for (int q = 0; q < 16; q++) {
                int4 b4 = bp4[q];
                int bs[4] = { b4.x, b4.y, b4.z, b4.w };
#pragma unroll
                for (int e = 0; e < 4; e++) {
                    if (bs[e] != cur) { atomicAdd(&Hh.cntL[cur], c); cur = bs[e]; c = 0.f; }
                    c += 1.f;
                }
            }
            atomicAdd(&Hh.cntL[cur], c);
        }
        __syncthreads();
        for (int idx = t; idx < 2048; idx += 256) {
            int b = idx >> 6, j = idx & 63;
            float pv = atomicAdd(&pooled[idx], 0.0f);   // coherent (L2) read
            Hh.ps[b][j] = pv / fmaxf(Hh.cntL[b], 1.0f);
        }
        __syncthreads();
        for (int idx = t; idx < 2048; idx += 256) {
            int b = idx >> 6, j = idx & 63;
            float v = pb1[j];
#pragma unroll 8
            for (int i = 0; i < 64; i++) v += Hh.ps[b][i] * pw1[j * 64 + i];
            Hh.p1[b][j] = leaky(v);
        }
        __syncthreads();
        for (int idx = t; idx < 1024; idx += 256) {
            int b = idx >> 5, j = idx & 31;
            float v = pb2[j];
#pragma unroll 8
            for (int i = 0; i < 64; i++) v += Hh.p1[b][i] * pw2[j * 64 + i];
            Hh.p2[b][j] = leaky(v);
        }
        __syncthreads();
        if (t < 32) {
            float v = pb3[0];
#pragma unroll 8
            for (int i = 0; i < 32; i++) v += Hh.p2[t][i] * pw3[i];
            out[t] = v;
        }
    }
}

// ----------------------------------------------------------------
extern "C" void kernel_launch(void* const* d_in, const int* in_sizes, int n_in,
                              void* d_out, int out_size, void* d_ws, size_t ws_size,
                              hipStream_t stream) {
    const float* x    = (const float*)d_in[0];
    const int*   eidx = (const int*)  d_in[1];
    const float* ea   = (const float*)d_in[2];
    const int*   bat  = (const int*)  d_in[3];
    const float* Win  = (const float*)d_in[4];
    const float* bin  = (const float*)d_in[5];
    const float* ew1  = (const float*)d_in[6];
    const float* eb1  = (const float*)d_in[7];
    const float* ew2  = (const float*)d_in[8];
    const float* eb2  = (const float*)d_in[9];
    const float* ew3  = (const float*)d_in[10];
    const float* eb3  = (const float*)d_in[11];
    const float* rw   = (const float*)d_in[12];
    const float* rb   = (const float*)d_in[13];
    const float* lg   = (const float*)d_in[14];
    const float* lb   = (const float*)d_in[15];
    const float* pw1  = (const float*)d_in[16];
    const float* pb1  = (const float*)d_in[17];
    const float* pw2  = (const float*)d_in[18];
    const float* pb2  = (const float*)d_in[19];
    const float* pw3  = (const float*)d_in[20];
    const float* pb3  = (const float*)d_in[21];
    float* out = (float*)d_out;

    float* ws     = (float*)d_ws;
    float* h      = ws;                          // 1048576 (first written by k_node l=0)
    float* agg    = ws + 1048576;                // 3 * 1048576
    float* deg    = ws + 4194304;                // 16384
    float* pooled = ws + 4210688;                // 2048
    int*   done   = (int*)(ws + 4212736);        // 64-float pad region (memset-zeroed)
    f16*   Bp     = (f16*)(ws + 4212800);        // 3 * 266240 f16

    const int* srcp = eidx;
    const int* dstp = eidx + N_EDGES;

    // one memset covers agg[3] + deg + pooled + done pad (contiguous)
    (void)hipMemsetAsync(agg, 0, (size_t)3164224 * sizeof(float), stream);

    k_setup<<<646, 256, 0, stream>>>(dstp, ew3, eb3, deg, Bp);

    for (int l = 0; l < NLAYERS; l++) {
        float* agg_l = agg + (size_t)l * N_NODES * H;
        int first = (l == 0) ? 1 : 0;
        int last  = (l == NLAYERS - 1) ? 1 : 0;
        k_msg <<<N_EDGES / 128, 256, 0, stream>>>(h, x, Win, bin, first,
                                                  ea, ew1 + l * 320, eb1 + l * 64,
                                                  ew2 + l * 4096, eb2 + l * 64,
                                                  Bp + (size_t)l * 266240,
                                                  srcp, dstp, agg_l);
        k_node<<<N_NODES / 64, 256, 0, stream>>>(agg_l, deg, rw + l * 4096, rb + l * 64,
                                                 lg + l * 64, lb + l * 64, h,
                                                 x, Win, bin, bat, pooled,
                                                 first, last, done,
                                                 pw1, pb1, pw2, pb2, pw3, pb3, out);
    }
}

// Round 12
// 311.839 us; speedup vs baseline: 1.9130x; 1.1423x over previous
//
#include <hip/hip_runtime.h>
#include <hip/hip_bf16.h>

#define N_NODES 16384
#define N_EDGES 65536
#define NB      32
#define H       64
#define NLAYERS 3
#define NEG     0.1f
#define LN_EPS  1e-5f

typedef _Float16 f16;
typedef _Float16 f16x2 __attribute__((ext_vector_type(2)));
typedef _Float16 f16x8 __attribute__((ext_vector_type(8)));
typedef __fp16   hf16x2 __attribute__((ext_vector_type(2)));
typedef float    f32x16 __attribute__((ext_vector_type(16)));

union F16x8 { f16x8 v; f16x2 p[4]; int4 i4; int2 i2[2]; };
union F16x2U { f16x2 h2; hf16x2 raw; unsigned int u; };
union F16U   { f16 h; unsigned short u; };

__device__ __forceinline__ f16x2 pkrtz(float a, float b) {
    F16x2U t; t.raw = __builtin_amdgcn_cvt_pkrtz(a, b); return t.h2;
}
__device__ __forceinline__ float leaky(float v) { return v > 0.f ? v : NEG * v; }

// ---------------------------------------------------------------- setup: inproj + degree + Bp prep (one dispatch)  [r0]
__global__ __launch_bounds__(256) void k_setup(const float* __restrict__ x,
                                               const float* __restrict__ Win,
                                               const float* __restrict__ bin,
                                               const int* __restrict__ dst,
                                               const float* __restrict__ ew3,
                                               const float* __restrict__ eb3,
                                               float* __restrict__ h,
                                               float* __restrict__ deg,
                                               f16* __restrict__ Bp) {
    int bid = blockIdx.x;
    if (bid < 4096) {                       // input projection
        int t = bid * 256 + threadIdx.x;
        int n = t >> 6, j = t & 63;
        const float* xr = x + n * 4;
        const float* wr = Win + j * 4;
        float v = bin[j] + xr[0] * wr[0] + xr[1] * wr[1] + xr[2] * wr[2] + xr[3] * wr[3];
        h[t] = leaky(v);
    } else if (bid < 4352) {                // degree atomics (deg pre-zeroed by memset)
        int e = (bid - 4096) * 256 + threadIdx.x;
        atomicAdd(&deg[dst[e]], 1.0f);
    } else {                                // Bp prep: 390 blocks = 1560 slots
        int tg    = (bid - 4352) * 256 + threadIdx.x;
        int lane  = tg & 63;
        int gslot = tg >> 6;
        int l     = gslot / 520;
        int slot  = gslot - l * 520;
        const float* ew3l = ew3 + (size_t)l * 262144;
        const float* eb3l = eb3 + (size_t)l * 4096;
        int i   = slot >> 3;
        int rem = slot & 7;
        int ks  = rem >> 1;
        int oq  = rem & 1;
        int o   = oq * 32 + (lane & 31);
        int k0  = ks * 16 + (lane >> 5) * 8;
        float v[8];
        if (i < 64) {
            const float* s = ew3l + ((size_t)(i * 64 + o)) * 64 + k0;
            float4 a = ((const float4*)s)[0];
            float4 b = ((const float4*)s)[1];
            v[0] = a.x; v[1] = a.y; v[2] = a.z; v[3] = a.w;
            v[4] = b.x; v[5] = b.y; v[6] = b.z; v[7] = b.w;
        } else {
#pragma unroll
            for (int j = 0; j < 8; j++) v[j] = eb3l[(k0 + j) * 64 + o];
        }
        union { int4 i4; f16 a[8]; } out;
#pragma unroll
        for (int j = 0; j < 8; j++) out.a[j] = (f16)v[j];
        *(int4*)(Bp + (size_t)l * 266240 + (size_t)slot * 512 + lane * 8) = out.i4;
    }
}

// ---------------------------------------------------------------- fused edge-MLP + bilinear MFMA GEMM + scatter  [r0, proven 52.4us]
#define HS_STRIDE 76   // u16; 152 B rows -> 2-way LDS banks (free)

__device__ __forceinline__ void loadB8(const f16* __restrict__ Bp, int c, int oq, int lane, F16x8* dstB) {
    const f16* base = Bp + (((size_t)(c * 16 + oq)) << 9) + lane * 8;
#pragma unroll
    for (int di = 0; di < 2; di++)
#pragma unroll
        for (int ks = 0; ks < 4; ks++)
            dstB[di * 4 + ks].i4 = *(const int4*)(base + ((di * 8 + ks * 2) << 9));
}
__device__ __forceinline__ void loadB4(const f16* __restrict__ Bp, int oq, int lane, F16x8* dstB) {
    const f16* base = Bp + (((size_t)(512 + oq)) << 9) + lane * 8;
#pragma unroll
    for (int ks = 0; ks < 4; ks++)
        dstB[ks].i4 = *(const int4*)(base + ((ks * 2) << 9));
}

__device__ __forceinline__ void msg_chunk2(int c, const F16x8* __restrict__ B,
                                           const unsigned short* hp0,
                                           const unsigned short* hp1,
                                           const f16x2 (*e2p)[4][4], f32x16* CC) {
    unsigned int rr0 = *(const unsigned int*)(hp0 + 2 * c);
    unsigned int rr1 = *(const unsigned int*)(hp1 + 2 * c);
    F16x2U h00, h01, h10, h11;
    h00.u = __builtin_amdgcn_perm(rr0, rr0, 0x01000100u);
    h10.u = __builtin_amdgcn_perm(rr0, rr0, 0x03020302u);
    h01.u = __builtin_amdgcn_perm(rr1, rr1, 0x01000100u);
    h11.u = __builtin_amdgcn_perm(rr1, rr1, 0x03020302u);
#pragma unroll
    for (int ks = 0; ks < 4; ks++) {
        F16x8 A00, A01, A10, A11;
#pragma unroll
        for (int r = 0; r < 4; r++) {
            A00.p[r] = h00.h2 * e2p[0][ks][r];
            A01.p[r] = h01.h2 * e2p[1][ks][r];
            A10.p[r] = h10.h2 * e2p[0][ks][r];
            A11.p[r] = h11.h2 * e2p[1][ks][r];
        }
        CC[0] = __builtin_amdgcn_mfma_f32_32x32x16_f16(A00.v, B[0 * 4 + ks].v, CC[0], 0, 0, 0);
        CC[1] = __builtin_amdgcn_mfma_f32_32x32x16_f16(A01.v, B[0 * 4 + ks].v, CC[1], 0, 0, 0);
        CC[2] = __builtin_amdgcn_mfma_f32_32x32x16_f16(A10.v, B[1 * 4 + ks].v, CC[2], 0, 0, 0);
        CC[3] = __builtin_amdgcn_mfma_f32_32x32x16_f16(A11.v, B[1 * 4 + ks].v, CC[3], 0, 0, 0);
    }
}

__global__ __launch_bounds__(256, 2) void k_msg(const float* __restrict__ h,
                                                const float* __restrict__ ea,
                                                const float* __restrict__ w1,
                                                const float* __restrict__ b1,
                                                const float* __restrict__ w2,
                                                const float* __restrict__ b2,
                                                const f16* __restrict__ Bp,
                                                const int* __restrict__ src,
                                                const int* __restrict__ dst,
                                                float* __restrict__ agg) {
    __shared__ __align__(16) unsigned short hsL[128 * HS_STRIDE];  // 19.5 KB
    __shared__ __align__(16) unsigned short e1L[128 * 72];         // 18 KB
    __shared__ __align__(16) unsigned short e2L[128 * 72];         // 18 KB
    __shared__ float eas[128 * 8];                                 // 4 KB
    __shared__ int dstL[128];

    const int t    = threadIdx.x;
    const int lane = t & 63;
    const int w    = t >> 6;
    const int eh   = w >> 1, oq = w & 1;
    const int m    = lane & 31;
    const int kp   = lane >> 5;
    const int eb   = blockIdx.x * 128;

    // ---- stage ea rows (5 -> pad 8)
    for (int idx = t; idx < 640; idx += 256) {
        int r = idx / 5, d = idx - r * 5;
        eas[r * 8 + d] = ea[(size_t)eb * 5 + idx];
    }
    // ---- stage h rows (gathered by src, fp32 -> f16): 2 threads per row
    {
        int e    = t >> 1;
        int half = t & 1;
        int nsrc = src[eb + e];
        const float4* hr = (const float4*)(h + (size_t)nsrc * 64 + half * 32);
        unsigned int* hrow = (unsigned int*)hsL + e * (HS_STRIDE / 2) + half * 16;
#pragma unroll
        for (int q = 0; q < 8; q++) {
            float4 v = hr[q];
            F16x2U p0, p1;
            p0.raw = __builtin_amdgcn_cvt_pkrtz(v.x, v.y);
            p1.raw = __builtin_amdgcn_cvt_pkrtz(v.z, v.w);
            hrow[q * 2 + 0] = p0.u;
            hrow[q * 2 + 1] = p1.u;
        }
        if (t < 128) dstL[t] = dst[eb + t];
    }
    __syncthreads();

    // ---- edge-MLP stage 1: e1 = leaky(ea @ w1^T + b1) -> e1L (f16)
    {
        int kk = t & 63;
        int eg = t >> 6;
        float w1r[5];
#pragma unroll
        for (int d = 0; d < 5; d++) w1r[d] = w1[kk * 5 + d];
        float b1r = b1[kk];
#pragma unroll 4
        for (int g = 0; g < 32; g++) {
            int row = eg * 32 + g;
            float4 a4 = *(const float4*)(eas + row * 8);
            float a5 = eas[row * 8 + 4];
            float v = b1r + a4.x * w1r[0] + a4.y * w1r[1] + a4.z * w1r[2] + a4.w * w1r[3] + a5 * w1r[4];
            F16U z; z.h = (f16)leaky(v);
            e1L[row * 72 + kk] = z.u;
        }
    }
    __syncthreads();

    // ---- edge-MLP stage 2 (MFMA): wave (eh, oq) -> tiles eh*2+tt, k_out half oq
    {
        F16x8 W2f[4];
#pragma unroll
        for (int ks = 0; ks < 4; ks++) {
            const float* s = w2 + (size_t)(oq * 32 + m) * 64 + ks * 16 + kp * 8;
            float4 a = ((const float4*)s)[0];
            float4 b = ((const float4*)s)[1];
            W2f[ks].p[0] = pkrtz(a.x, a.y);
            W2f[ks].p[1] = pkrtz(a.z, a.w);
            W2f[ks].p[2] = pkrtz(b.x, b.y);
            W2f[ks].p[3] = pkrtz(b.z, b.w);
        }
        float b2r = b2[oq * 32 + m];
#pragma unroll
        for (int tt = 0; tt < 2; tt++) {
            f32x16 C2 = {0,0,0,0,0,0,0,0,0,0,0,0,0,0,0,0};
#pragma unroll
            for (int ks = 0; ks < 4; ks++) {
                F16x8 A;
                A.i4 = *(const int4*)(e1L + (size_t)((eh * 2 + tt) * 32 + m) * 72 + ks * 16 + kp * 8);
                C2 = __builtin_amdgcn_mfma_f32_32x32x16_f16(A.v, W2f[ks].v, C2, 0, 0, 0);
            }
#pragma unroll
            for (int reg = 0; reg < 16; reg++) {
                int r = (reg & 3) + 8 * (reg >> 2) + 4 * kp;
                F16U z; z.h = (f16)leaky(C2[reg] + b2r);
                e2L[((eh * 2 + tt) * 32 + r) * 72 + oq * 32 + m] = z.u;
            }
        }
    }
    __syncthreads();

    // ---- read e2 A-operand pairs for this wave's 2 tiles (full k)
    f16x2 e2p[2][4][4];
#pragma unroll
    for (int tt = 0; tt < 2; tt++) {
#pragma unroll
        for (int ks = 0; ks < 4; ks++) {
            F16x8 q;
            q.i4 = *(const int4*)(e2L + (size_t)((eh * 2 + tt) * 32 + m) * 72 + ks * 16 + kp * 8);
            e2p[tt][ks][0] = q.p[0]; e2p[tt][ks][1] = q.p[1];
            e2p[tt][ks][2] = q.p[2]; e2p[tt][ks][3] = q.p[3];
        }
    }

    f32x16 CC[4];
#pragma unroll
    for (int q = 0; q < 4; q++)
#pragma unroll
        for (int r = 0; r < 16; r++) CC[q][r] = 0.f;

    const unsigned short* hp0 = hsL + ((eh * 2 + 0) * 32 + m) * HS_STRIDE;
    const unsigned short* hp1 = hsL + ((eh * 2 + 1) * 32 + m) * HS_STRIDE;

    // ---- STATIC double-buffered barrier-free K-loop
    F16x8 B0[8], B1[8];
    loadB8(Bp, 0, oq, lane, B0);
    loadB8(Bp, 1, oq, lane, B1);
    for (int it = 0; it < 15; it++) {
        int c = it * 2;
        msg_chunk2(c,     B0, hp0, hp1, e2p, CC);  loadB8(Bp, c + 2, oq, lane, B0);
        msg_chunk2(c + 1, B1, hp0, hp1, e2p, CC);  loadB8(Bp, c + 3, oq, lane, B1);
    }
    msg_chunk2(30, B0, hp0, hp1, e2p, CC);
    loadB4(Bp, oq, lane, B0);               // bias frags into B0[0..3]
    msg_chunk2(31, B1, hp0, hp1, e2p, CC);

    // ---- bias chunk: A = h itself (k plays the i role), B = eb3 frags
#pragma unroll
    for (int ks = 0; ks < 4; ks++) {
        int koff = (ks * 16 + kp * 8) * 2;
        const char* r0p = (const char*)hsL + (size_t)((eh * 2 + 0) * 32 + m) * (HS_STRIDE * 2) + koff;
        const char* r1p = (const char*)hsL + (size_t)((eh * 2 + 1) * 32 + m) * (HS_STRIDE * 2) + koff;
        F16x8 A0, A1;
        A0.i2[0] = *(const int2*)(r0p); A0.i2[1] = *(const int2*)(r0p + 8);
        A1.i2[0] = *(const int2*)(r1p); A1.i2[1] = *(const int2*)(r1p + 8);
        CC[0] = __builtin_amdgcn_mfma_f32_32x32x16_f16(A0.v, B0[ks].v, CC[0], 0, 0, 0);
        CC[1] = __builtin_amdgcn_mfma_f32_32x32x16_f16(A1.v, B0[ks].v, CC[1], 0, 0, 0);
    }

    // ---- merge i-parity chains, scatter
    int o = oq * 32 + m;
#pragma unroll
    for (int reg = 0; reg < 16; reg++) {
        int r = (reg & 3) + 8 * (reg >> 2) + 4 * kp;
        atomicAdd(&agg[(size_t)dstL[(eh * 2 + 0) * 32 + r] * 64 + o], CC[0][reg] + CC[2][reg]);
    }
#pragma unroll
    for (int reg = 0; reg < 16; reg++) {
        int r = (reg & 3) + 8 * (reg >> 2) + 4 * kp;
        atomicAdd(&agg[(size_t)dstL[(eh * 2 + 1) * 32 + r] * 64 + o], CC[1][reg] + CC[3][reg]);
    }
}

// ---------------------------------------------------------------- node update: MFMA root GEMM + PARALLEL LN + residual (+pool on last)
// ROUND-12: LN restructured from 16 SERIAL per-wave iterations (each with two
// 6-deep dependent shfl_xor trees = the latency chain that made k_node ~50-68us
// at 2% VALUBusy) to 4-threads-per-node data-parallel form: 16 in-register adds
// + 2-hop shfl_xor butterfly; agg read vectorized float4 (was 16 scattered
// dwords); h read/write float4. Pooling pass unchanged (shfl-free, cheap).
__global__ __launch_bounds__(256) void k_node(const float* __restrict__ agg,
                                              const float* __restrict__ deg,
                                              const float* __restrict__ rw,
                                              const float* __restrict__ rb,
                                              const float* __restrict__ lg,
                                              const float* __restrict__ lb,
                                              float* __restrict__ h,
                                              const int* __restrict__ batch,
                                              float* __restrict__ pooled,
                                              int last) {
    __shared__ __align__(16) unsigned short hA[64 * 72];
    __shared__ float outL[64][68];
    int t = threadIdx.x;
    int nb = blockIdx.x * 64;
    int lane = t & 63, w = t >> 6;
    int nq = w >> 1, oq = w & 1;
    int m = lane & 31, kp = lane >> 5;

    {
        int r = t >> 2, c0 = (t & 3) * 16;
        const float4* hr = (const float4*)(h + (size_t)(nb + r) * 64 + c0);
        unsigned int* drow = (unsigned int*)hA + r * 36 + c0 / 2;
#pragma unroll
        for (int q = 0; q < 4; q++) {
            float4 v = hr[q];
            F16x2U p0, p1;
            p0.raw = __builtin_amdgcn_cvt_pkrtz(v.x, v.y);
            p1.raw = __builtin_amdgcn_cvt_pkrtz(v.z, v.w);
            drow[q * 2] = p0.u; drow[q * 2 + 1] = p1.u;
        }
    }
    F16x8 Bf[4];
#pragma unroll
    for (int ks = 0; ks < 4; ks++) {
        const float* s = rw + (size_t)(oq * 32 + m) * 64 + ks * 16 + kp * 8;
        float4 a = ((const float4*)s)[0];
        float4 b = ((const float4*)s)[1];
        Bf[ks].p[0] = pkrtz(a.x, a.y);
        Bf[ks].p[1] = pkrtz(a.z, a.w);
        Bf[ks].p[2] = pkrtz(b.x, b.y);
        Bf[ks].p[3] = pkrtz(b.z, b.w);
    }
    __syncthreads();

    f32x16 C = {0,0,0,0,0,0,0,0,0,0,0,0,0,0,0,0};
#pragma unroll
    for (int ks = 0; ks < 4; ks++) {
        F16x8 A;
        A.i4 = *(const int4*)(hA + (size_t)(nq * 32 + m) * 72 + ks * 16 + kp * 8);
        C = __builtin_amdgcn_mfma_f32_32x32x16_f16(A.v, Bf[ks].v, C, 0, 0, 0);
    }

    int o = oq * 32 + m;
#pragma unroll
    for (int reg = 0; reg < 16; reg++) {
        int r = (reg & 3) + 8 * (reg >> 2) + 4 * kp;
        outL[nq * 32 + r][o] = C[reg] + rb[o];      // agg added in LN phase (vectorized there)
    }
    __syncthreads();

    // ---- parallel LN: 4 threads per node, each owns 16 channels
    {
        int node = t >> 2, c0 = (t & 3) * 16;
        size_t gb = (size_t)(nb + node) * 64 + c0;
        float vdeg = fmaxf(deg[nb + node], 1.0f);
        float v[16];
#pragma unroll
        for (int q = 0; q < 4; q++) {
            float4 a = *(const float4*)(agg + gb + q * 4);
            v[q * 4 + 0] = outL[node][c0 + q * 4 + 0] + a.x / vdeg;
            v[q * 4 + 1] = outL[node][c0 + q * 4 + 1] + a.y / vdeg;
            v[q * 4 + 2] = outL[node][c0 + q * 4 + 2] + a.z / vdeg;
            v[q * 4 + 3] = outL[node][c0 + q * 4 + 3] + a.w / vdeg;
        }
        float s = 0.f;
#pragma unroll
        for (int i = 0; i < 16; i++) s += v[i];
        s += __shfl_xor(s, 1);
        s += __shfl_xor(s, 2);
        float mu = s * (1.f / 64.f);
        float vs = 0.f;
#pragma unroll
        for (int i = 0; i < 16; i++) { float d = v[i] - mu; vs += d * d; }
        vs += __shfl_xor(vs, 1);
        vs += __shfl_xor(vs, 2);
        float rs = rsqrtf(vs * (1.f / 64.f) + LN_EPS);
        float4 gv[4], bv[4], hp[4];
#pragma unroll
        for (int q = 0; q < 4; q++) {
            gv[q] = *(const float4*)(lg + c0 + q * 4);
            bv[q] = *(const float4*)(lb + c0 + q * 4);
            hp[q] = *(const float4*)(h + gb + q * 4);
        }
        const float* gf = (const float*)gv;
        const float* bf = (const float*)bv;
        const float* hf = (const float*)hp;
        float hn[16];
#pragma unroll
        for (int i = 0; i < 16; i++) {
            float ov = (v[i] - mu) * rs * gf[i] + bf[i];
            hn[i] = leaky(ov) + hf[i];
        }
#pragma unroll
        for (int q = 0; q < 4; q++) {
            float4 hw; hw.x = hn[q * 4]; hw.y = hn[q * 4 + 1]; hw.z = hn[q * 4 + 2]; hw.w = hn[q * 4 + 3];
            *(float4*)(h + gb + q * 4) = hw;
        }
#pragma unroll
        for (int i = 0; i < 16; i++) outL[node][c0 + i] = hn[i];
    }

    // ---- pooling (last layer only): shfl-free, wave-serial over 16 nodes
    if (last) {
        __syncthreads();
        float accp = 0.f;
        int cur = batch[nb + w * 16];
        for (int q = 0; q < 16; q++) {
            int n = w * 16 + q;
            float hv = outL[n][lane];
            int b = batch[nb + n];
            if (b != cur) { atomicAdd(&pooled[cur * 64 + lane], accp); accp = 0.f; cur = b; }
            accp += hv;
        }
        atomicAdd(&pooled[cur * 64 + lane], accp);
    }
}

// ---------------------------------------------------------------- prediction head (1 block; computes cnt from sorted batch)  [r0]
__global__ __launch_bounds__(256) void k_head(const float* __restrict__ pooled,
                                              const int* __restrict__ batch,
                                              const float* __restrict__ pw1, const float* __restrict__ pb1,
                                              const float* __restrict__ pw2, const float* __restrict__ pb2,
                                              const float* __restrict__ pw3, const float* __restrict__ pb3,
                                              float* __restrict__ out) {
    __shared__ float cntL[32];
    __shared__ float ps[32][64];
    __shared__ float p1[32][64];
    __shared__ float p2[32][32];
    int t = threadIdx.x;
    if (t < 32) cntL[t] = 0.f;
    __syncthreads();
    {
        const int4* bp4 = (const int4*)(batch + t * 64);
        int cur = batch[t * 64];
        float c = 0.f;
        for (int q = 0; q < 16; q++) {
            int4 b4 = bp4[q];
            int bs[4] = { b4.x, b4.y, b4.z, b4.w };
#pragma unroll
            for (int e = 0; e < 4; e++) {
                if (bs[e] != cur) { atomicAdd(&cntL[cur], c); cur = bs[e]; c = 0.f; }
                c += 1.f;
            }
        }
        atomicAdd(&cntL[cur], c);
    }
    __syncthreads();
    for (int idx = t; idx < 2048; idx += 256) {
        int b = idx >> 6, j = idx & 63;
        ps[b][j] = pooled[idx] / fmaxf(cntL[b], 1.0f);
    }
    __syncthreads();
    for (int idx = t; idx < 2048; idx += 256) {
        int b = idx >> 6, j = idx & 63;
        float v = pb1[j];
#pragma unroll 8
        for (int i = 0; i < 64; i++) v += ps[b][i] * pw1[j * 64 + i];
        p1[b][j] = leaky(v);
    }
    __syncthreads();
    for (int idx = t; idx < 1024; idx += 256) {
        int b = idx >> 5, j = idx & 31;
        float v = pb2[j];
#pragma unroll 8
        for (int i = 0; i < 64; i++) v += p1[b][i] * pw2[j * 64 + i];
        p2[b][j] = leaky(v);
    }
    __syncthreads();
    if (t < 32) {
        float v = pb3[0];
#pragma unroll 8
        for (int i = 0; i < 32; i++) v += p2[t][i] * pw3[i];
        out[t] = v;
    }
}

// ----------------------------------------------------------------
extern "C" void kernel_launch(void* const* d_in, const int* in_sizes, int n_in,
                              void* d_out, int out_size, void* d_ws, size_t ws_size,
                              hipStream_t stream) {
    const float* x    = (const float*)d_in[0];
    const int*   eidx = (const int*)  d_in[1];
    const float* ea   = (const float*)d_in[2];
    const int*   bat  = (const int*)  d_in[3];
    const float* Win  = (const float*)d_in[4];
    const float* bin  = (const float*)d_in[5];
    const float* ew1  = (const float*)d_in[6];
    const float* eb1  = (const float*)d_in[7];
    const float* ew2  = (const float*)d_in[8];
    const float* eb2  = (const float*)d_in[9];
    const float* ew3  = (const float*)d_in[10];
    const float* eb3  = (const float*)d_in[11];
    const float* rw   = (const float*)d_in[12];
    const float* rb   = (const float*)d_in[13];
    const float* lg   = (const float*)d_in[14];
    const float* lb   = (const float*)d_in[15];
    const float* pw1  = (const float*)d_in[16];
    const float* pb1  = (const float*)d_in[17];
    const float* pw2  = (const float*)d_in[18];
    const float* pb2  = (const float*)d_in[19];
    const float* pw3  = (const float*)d_in[20];
    const float* pb3  = (const float*)d_in[21];
    float* out = (float*)d_out;

    float* ws     = (float*)d_ws;
    float* h      = ws;                          // 1048576
    float* agg    = ws + 1048576;                // 3 * 1048576
    float* deg    = ws + 4194304;                // 16384
    float* pooled = ws + 4210688;                // 2048 (+64 pad)
    f16*   Bp     = (f16*)(ws + 4212800);        // 3 * 266240 f16

    const int* srcp = eidx;
    const int* dstp = eidx + N_EDGES;

    // one memset covers agg[3] + deg + pooled (contiguous)
    (void)hipMemsetAsync(agg, 0, (size_t)3164224 * sizeof(float), stream);

    k_setup<<<4742, 256, 0, stream>>>(x, Win, bin, dstp, ew3, eb3, h, deg, Bp);

    for (int l = 0; l < NLAYERS; l++) {
        float* agg_l = agg + (size_t)l * N_NODES * H;
        k_msg <<<N_EDGES / 128, 256, 0, stream>>>(h, ea, ew1 + l * 320, eb1 + l * 64,
                                                  ew2 + l * 4096, eb2 + l * 64,
                                                  Bp + (size_t)l * 266240,
                                                  srcp, dstp, agg_l);
        k_node<<<N_NODES / 64, 256, 0, stream>>>(agg_l, deg, rw + l * 4096, rb + l * 64,
                                                 lg + l * 64, lb + l * 64, h,
                                                 bat, pooled, l == NLAYERS - 1 ? 1 : 0);
    }

    k_head<<<1, 256, 0, stream>>>(pooled, bat, pw1, pb1, pw2, pb2, pw3, pb3, out);
}